// Round 6
// baseline (1541.141 us; speedup 1.0000x reference)
//
#include <hip/hip_runtime.h>

// ---------------------------------------------------------------------------
// LSTMGRUHybrid: B=512, T=512, D=128, H=128 (4H=512), G=128 (3G=384), F=160, C=64
// Round 6: revert to round-4 pipeline (precomputed gx GEMMs; they beat in-scan
// x-proj because padded-M fusion doubles MFMA pipe time). Changes vs round 4:
//   - scans use HSTR=140 (0 LDS bank conflicts, verified round 5)
//   - prep_x deleted: LSTM gemm reads fp32 x directly, converts during staging
// Pipeline: prep_misc, gemm_x32(LSTM gx), lstm_scan, ln_pass,
//           gemm_nt(GRU gx), gru_scan, head.
// ---------------------------------------------------------------------------

typedef __attribute__((ext_vector_type(8))) short bf16x8;
typedef __attribute__((ext_vector_type(4))) float f32x4;
typedef __attribute__((ext_vector_type(4))) int i32x4;
typedef unsigned short u16;
typedef unsigned int u32;

#define BT 262144          // B*T
#define TT 512
#define HSTR 140           // hbuf row stride in u16 (byte 280 = 24 mod 128)

__device__ __forceinline__ u16 f2bf(float f) {
  u32 u = __builtin_bit_cast(u32, f);
  u += 0x7fffu + ((u >> 16) & 1u);
  return (u16)(u >> 16);
}
__device__ __forceinline__ float bf2f(u16 h) {
  return __builtin_bit_cast(float, (u32)h << 16);
}
__device__ __forceinline__ u32 packbf2(float a, float b) {
  return (u32)f2bf(a) | ((u32)f2bf(b) << 16);
}
__device__ __forceinline__ bf16x8 ldg8(const u16* p) {
  return __builtin_bit_cast(bf16x8, *(const i32x4*)p);
}
__device__ __forceinline__ void g2lds16(const void* g, void* l) {
  __builtin_amdgcn_global_load_lds((const __attribute__((address_space(1))) void*)g,
                                   (__attribute__((address_space(3))) void*)l, 16, 0, 0);
}
// fast sigmoid/tanh: v_rcp instead of IEEE div sequence
__device__ __forceinline__ float frcp(float x) { return __builtin_amdgcn_rcpf(x); }
__device__ __forceinline__ float sigm(float x) { return frcp(1.f + __expf(-x)); }
__device__ __forceinline__ float tanh_f(float x) {
  return 1.f - 2.f * frcp(__expf(2.f * x) + 1.f);
}
// barrier draining LDS only (vmcnt stays outstanding: gx prefetch + lout
// stores stay off the critical path). 0xC07F = vmcnt(63) expcnt(7) lgkm(0)
__device__ __forceinline__ void scan_barrier() {
  __asm__ volatile("" ::: "memory");
  __builtin_amdgcn_s_waitcnt(0xC07F);
  __builtin_amdgcn_s_barrier();
  __asm__ volatile("" ::: "memory");
}

// ---------------------------------------------------------------------------
// prep kernel
// ---------------------------------------------------------------------------
__global__ void prep_misc(
    const float* __restrict__ wihl, const float* __restrict__ whhl,
    const float* __restrict__ wihg, const float* __restrict__ whhg,
    const float* __restrict__ bihl, const float* __restrict__ bhhl,
    const float* __restrict__ fc1W, const float* __restrict__ fcoW,
    u16* __restrict__ wihlb, u16* __restrict__ whhlb,
    u16* __restrict__ wihgb, u16* __restrict__ whhgb,
    float* __restrict__ biasl, float* __restrict__ fc1Wt, float* __restrict__ fcoWt) {
  int i = blockIdx.x * 256 + threadIdx.x;
  if (i < 65536) {
    wihlb[i] = f2bf(wihl[i]);
  } else if (i < 131072) {
    int k = i - 65536; whhlb[k] = f2bf(whhl[k]);
  } else if (i < 180224) {
    int k = i - 131072; wihgb[k] = f2bf(wihg[k]);
  } else if (i < 229376) {
    int k = i - 180224; whhgb[k] = f2bf(whhg[k]);
  } else if (i < 229888) {
    int k = i - 229376; biasl[k] = bihl[k] + bhhl[k];
  } else if (i < 250368) {
    int k = i - 229888;                       // fc1Wt[g*160+f] = fc1W[f*128+g]
    fc1Wt[k] = fc1W[(k % 160) * 128 + (k / 160)];
  } else if (i < 260608) {
    int k = i - 250368;                       // fcoWt[f*64+c] = fcoW[c*160+f]
    fcoWt[k] = fcoW[(k % 64) * 160 + (k / 64)];
  }
}

// ---------------------------------------------------------------------------
// gemm_x32: C[M,N] bf16 = Afp32[M,128] @ Bw[N,128]^T + bias[N]; tile 128x128.
// A read as fp32 and converted to bf16 during LDS staging (prep_x fused).
// ---------------------------------------------------------------------------
__global__ __launch_bounds__(256) void gemm_x32(
    const float* __restrict__ A, const u16* __restrict__ Bw,
    const float* __restrict__ bias, u16* __restrict__ C, int N) {
  __shared__ __align__(16) u16 sA[128 * 128];
  __shared__ __align__(16) u16 sB[128 * 128];
  const int tid = threadIdx.x;
  const int w = tid >> 6, l = tid & 63;
  const size_t m0 = (size_t)blockIdx.x * 128;
  const int n0 = blockIdx.y * 128;
  const char* gB = (const char*)(Bw + (size_t)n0 * 128);
  char* lB = (char*)sB;
#pragma unroll
  for (int i = 0; i < 8; i++) {
    int ubase = ((i * 4 + w) << 10);
    g2lds16(gB + ubase + (l << 4), lB + ubase);
  }
  // A: fp32 -> bf16 convert-stage (64 elems per thread as 16 float4)
  {
    const float* gA = A + m0 * 128;
#pragma unroll
    for (int i = 0; i < 16; i++) {
      int e = (i * 256 + tid) * 4;
      float4 v = *(const float4*)(gA + e);
      *(uint2*)(sA + e) = make_uint2(packbf2(v.x, v.y), packbf2(v.z, v.w));
    }
  }
  __syncthreads();
  const int mq = (w >> 1) * 64, nq = (w & 1) * 64;
  f32x4 acc[4][4];
#pragma unroll
  for (int i = 0; i < 4; i++)
#pragma unroll
    for (int j = 0; j < 4; j++) acc[i][j] = (f32x4){0.f, 0.f, 0.f, 0.f};
#pragma unroll
  for (int k0 = 0; k0 < 4; k0++) {
    const int koff = k0 * 32 + (l >> 4) * 8;
    bf16x8 af[4], bf[4];
#pragma unroll
    for (int i = 0; i < 4; i++) af[i] = ldg8(&sA[(mq + i * 16 + (l & 15)) * 128 + koff]);
#pragma unroll
    for (int j = 0; j < 4; j++) bf[j] = ldg8(&sB[(nq + j * 16 + (l & 15)) * 128 + koff]);
#pragma unroll
    for (int i = 0; i < 4; i++)
#pragma unroll
      for (int j = 0; j < 4; j++)
        acc[i][j] = __builtin_amdgcn_mfma_f32_16x16x32_bf16(af[i], bf[j], acc[i][j], 0, 0, 0);
  }
  float bv[4];
#pragma unroll
  for (int j = 0; j < 4; j++) bv[j] = bias[n0 + nq + j * 16 + (l & 15)];
  __syncthreads();
  u16* sOut = sA;  // reuse
#pragma unroll
  for (int i = 0; i < 4; i++)
#pragma unroll
    for (int j = 0; j < 4; j++)
#pragma unroll
      for (int r = 0; r < 4; r++)
        sOut[(mq + i * 16 + (l >> 4) * 4 + r) * 128 + nq + j * 16 + (l & 15)] =
            f2bf(acc[i][j][r] + bv[j]);
  __syncthreads();
#pragma unroll
  for (int p = 0; p < 8; p++) {
    int e = (p * 256 + tid) * 8;
    int row = e >> 7, col = e & 127;
    *(i32x4*)(C + (m0 + row) * (size_t)N + n0 + col) = *(const i32x4*)&sOut[e];
  }
}

// ---------------------------------------------------------------------------
// gemm_nt: C[M,N] bf16 = A[M,128] bf16 @ Bw[N,128]^T + bias[N]; tile 128x128
// ---------------------------------------------------------------------------
__global__ __launch_bounds__(256) void gemm_nt(
    const u16* __restrict__ A, const u16* __restrict__ Bw,
    const float* __restrict__ bias, u16* __restrict__ C, int N) {
  __shared__ __align__(16) u16 sA[128 * 128];
  __shared__ __align__(16) u16 sB[128 * 128];
  const int tid = threadIdx.x;
  const int w = tid >> 6, l = tid & 63;
  const size_t m0 = (size_t)blockIdx.x * 128;
  const int n0 = blockIdx.y * 128;
  const char* gA = (const char*)(A + m0 * 128);
  const char* gB = (const char*)(Bw + (size_t)n0 * 128);
  char* lA = (char*)sA;
  char* lB = (char*)sB;
#pragma unroll
  for (int i = 0; i < 8; i++) {
    int ubase = (w * 8 + i) << 10;
    int off = ubase + (l << 4);
    g2lds16(gA + off, lA + ubase);
    g2lds16(gB + off, lB + ubase);
  }
  __syncthreads();
  const int mq = (w >> 1) * 64, nq = (w & 1) * 64;
  f32x4 acc[4][4];
#pragma unroll
  for (int i = 0; i < 4; i++)
#pragma unroll
    for (int j = 0; j < 4; j++) acc[i][j] = (f32x4){0.f, 0.f, 0.f, 0.f};
#pragma unroll
  for (int k0 = 0; k0 < 4; k0++) {
    const int koff = k0 * 32 + (l >> 4) * 8;
    bf16x8 af[4], bf[4];
#pragma unroll
    for (int i = 0; i < 4; i++) af[i] = ldg8(&sA[(mq + i * 16 + (l & 15)) * 128 + koff]);
#pragma unroll
    for (int j = 0; j < 4; j++) bf[j] = ldg8(&sB[(nq + j * 16 + (l & 15)) * 128 + koff]);
#pragma unroll
    for (int i = 0; i < 4; i++)
#pragma unroll
      for (int j = 0; j < 4; j++)
        acc[i][j] = __builtin_amdgcn_mfma_f32_16x16x32_bf16(af[i], bf[j], acc[i][j], 0, 0, 0);
  }
  float bv[4];
#pragma unroll
  for (int j = 0; j < 4; j++) bv[j] = bias[n0 + nq + j * 16 + (l & 15)];
  __syncthreads();
  u16* sOut = sA;  // reuse
#pragma unroll
  for (int i = 0; i < 4; i++)
#pragma unroll
    for (int j = 0; j < 4; j++)
#pragma unroll
      for (int r = 0; r < 4; r++)
        sOut[(mq + i * 16 + (l >> 4) * 4 + r) * 128 + nq + j * 16 + (l & 15)] =
            f2bf(acc[i][j][r] + bv[j]);
  __syncthreads();
#pragma unroll
  for (int p = 0; p < 8; p++) {
    int e = (p * 256 + tid) * 8;
    int row = e >> 7, col = e & 127;
    *(i32x4*)(C + (m0 + row) * (size_t)N + n0 + col) = *(const i32x4*)&sOut[e];
  }
}

// ---------------------------------------------------------------------------
// LSTM scan. 128 blocks x 512 thr; 4 batch rows/block at MFMA rows {0,4,8,12}
// (each lane owns one gate element, C reg 0). Wave w owns hidden cols
// [w*16,w*16+16); its 4 MFMA N-tiles are the 4 gates at that col slice.
// ---------------------------------------------------------------------------
__global__ __launch_bounds__(512) void lstm_scan(
    const u16* __restrict__ gx,   // [BT][512] bf16 (x-proj + bih + bhh)
    const u16* __restrict__ whh,  // [512][128] bf16
    u16* __restrict__ lout) {     // [B][T][128] bf16 raw h (LN applied later)
  const int tid = threadIdx.x;
  const int w = tid >> 6, l = tid & 63;
  const int hc = l & 15, q = l >> 4;
  const int col = w * 16 + hc;
  const int b0 = blockIdx.x * 4;
  const int mrow = q * 4;
  __shared__ __align__(16) u16 hb0[16 * HSTR];
  __shared__ __align__(16) u16 hb1[16 * HSTR];

  bf16x8 wf[4][4];
#pragma unroll
  for (int g = 0; g < 4; g++)
#pragma unroll
    for (int k0 = 0; k0 < 4; k0++)
      wf[g][k0] = ldg8(&whh[(g * 128 + col) * 128 + k0 * 32 + q * 8]);

  float c = 0.f;
  u32 goff = (u32)(b0 + q) * (TT * 512) + col;
  u32 loff = (u32)(b0 + q) * (TT * 128) + col;
  const int hbase = hc * HSTR + q * 8;
  for (int i = tid; i < 16 * HSTR; i += 512) { hb0[i] = 0; hb1[i] = 0; }

  u16 ga[4], gb[4];
#pragma unroll
  for (int g = 0; g < 4; g++) ga[g] = gx[goff + g * 128];
  goff += 512;
  scan_barrier();

  auto step = [&](u16 (&gc)[4], u16 (&gp)[4], const u16* hrd, u16* hwr) {
    // prefetch t+1 (vmcnt NOT drained at barrier; lands by next gate phase)
#pragma unroll
    for (int g = 0; g < 4; g++) gp[g] = gx[goff + g * 128];
    goff += 512;
    // h(t-1) @ Whh^T  (A rows {0,4,8,12} hold the 4 batch rows; rest zero)
    bf16x8 af[4];
#pragma unroll
    for (int k0 = 0; k0 < 4; k0++) af[k0] = ldg8(&hrd[hbase + k0 * 32]);
    f32x4 acc[4];
#pragma unroll
    for (int g = 0; g < 4; g++) acc[g] = (f32x4){0.f, 0.f, 0.f, 0.f};
#pragma unroll
    for (int k0 = 0; k0 < 4; k0++)
#pragma unroll
      for (int g = 0; g < 4; g++)
        acc[g] = __builtin_amdgcn_mfma_f32_16x16x32_bf16(af[k0], wf[g][k0], acc[g], 0, 0, 0);
    // gates (single element per lane: C reg 0 = batch b0+q, hidden col)
    float pi = acc[0][0] + bf2f(gc[0]);
    float pf = acc[1][0] + bf2f(gc[1]);
    float pg = acc[2][0] + bf2f(gc[2]);
    float po = acc[3][0] + bf2f(gc[3]);
    c = sigm(pf) * c + sigm(pi) * tanh_f(pg);
    float h = sigm(po) * tanh_f(c);
    u16 hv = f2bf(h);
    hwr[mrow * HSTR + col] = hv;
    lout[loff] = hv;
    loff += 128;
    scan_barrier();
  };

#pragma unroll 1
  for (int t2 = 0; t2 < TT; t2 += 2) {
    step(ga, gb, hb0, hb1);
    step(gb, ga, hb1, hb0);
  }
}

// ---------------------------------------------------------------------------
// In-place row LayerNorm over [BT][128] bf16. One wave per row.
// ---------------------------------------------------------------------------
__global__ __launch_bounds__(256) void ln_pass(
    u16* __restrict__ buf, const float* __restrict__ g, const float* __restrict__ b) {
  const size_t row = (size_t)blockIdx.x * 4 + (threadIdx.x >> 6);
  const int l = threadIdx.x & 63;
  u16* p = buf + row * 128 + l * 2;
  u32 v = *(const u32*)p;
  float a0 = bf2f((u16)v), a1 = bf2f((u16)(v >> 16));
  float s1 = a0 + a1, s2 = a0 * a0 + a1 * a1;
#pragma unroll
  for (int m = 1; m < 64; m <<= 1) { s1 += __shfl_xor(s1, m); s2 += __shfl_xor(s2, m); }
  float mean = s1 * 0.0078125f;
  float var = s2 * 0.0078125f - mean * mean;
  float rs = rsqrtf(var + 1e-5f);
  float2 gg = *(const float2*)(g + l * 2);
  float2 bb = *(const float2*)(b + l * 2);
  float y0 = (a0 - mean) * rs * gg.x + bb.x;
  float y1 = (a1 - mean) * rs * gg.y + bb.y;
  *(u32*)p = packbf2(y0, y1);
}

// ---------------------------------------------------------------------------
// GRU scan -> final hidden only. 128 blocks x 4 rows, same row-spreading.
// ---------------------------------------------------------------------------
__global__ __launch_bounds__(512) void gru_scan(
    const u16* __restrict__ gx,   // [BT][384] bf16 (x-proj + bih)
    const u16* __restrict__ whh,  // [384][128] bf16
    const float* __restrict__ bhh,
    float* __restrict__ hlast) {  // [512][128] fp32
  const int tid = threadIdx.x;
  const int w = tid >> 6, l = tid & 63;
  const int hc = l & 15, q = l >> 4;
  const int col = w * 16 + hc;
  const int b0 = blockIdx.x * 4;
  const int mrow = q * 4;
  __shared__ __align__(16) u16 hb0[16 * HSTR];
  __shared__ __align__(16) u16 hb1[16 * HSTR];

  bf16x8 wf[3][4];
#pragma unroll
  for (int g = 0; g < 3; g++)
#pragma unroll
    for (int k0 = 0; k0 < 4; k0++)
      wf[g][k0] = ldg8(&whh[(g * 128 + col) * 128 + k0 * 32 + q * 8]);

  const float bhr = bhh[col], bhz = bhh[128 + col], bhn = bhh[256 + col];
  float hp = 0.f;
  u32 goff = (u32)(b0 + q) * (TT * 384) + col;
  const int hbase = hc * HSTR + q * 8;
  for (int i = tid; i < 16 * HSTR; i += 512) { hb0[i] = 0; hb1[i] = 0; }

  u16 ga[3], gb[3];
#pragma unroll
  for (int g = 0; g < 3; g++) ga[g] = gx[goff + g * 128];
  goff += 384;
  scan_barrier();

  auto step = [&](u16 (&gc)[3], u16 (&gp)[3], const u16* hrd, u16* hwr) {
#pragma unroll
    for (int g = 0; g < 3; g++) gp[g] = gx[goff + g * 128];
    goff += 384;
    bf16x8 af[4];
#pragma unroll
    for (int k0 = 0; k0 < 4; k0++) af[k0] = ldg8(&hrd[hbase + k0 * 32]);
    f32x4 acc[3];
#pragma unroll
    for (int g = 0; g < 3; g++) acc[g] = (f32x4){0.f, 0.f, 0.f, 0.f};
#pragma unroll
    for (int k0 = 0; k0 < 4; k0++)
#pragma unroll
      for (int g = 0; g < 3; g++)
        acc[g] = __builtin_amdgcn_mfma_f32_16x16x32_bf16(af[k0], wf[g][k0], acc[g], 0, 0, 0);
    float rr = sigm(bf2f(gc[0]) + acc[0][0] + bhr);
    float zz = sigm(bf2f(gc[1]) + acc[1][0] + bhz);
    float nn = tanh_f(bf2f(gc[2]) + rr * (acc[2][0] + bhn));
    hp = nn + zz * (hp - nn);
    hwr[mrow * HSTR + col] = f2bf(hp);
    scan_barrier();
  };

#pragma unroll 1
  for (int t2 = 0; t2 < TT; t2 += 2) {
    step(ga, gb, hb0, hb1);
    step(gb, ga, hb1, hb0);
  }
  hlast[(size_t)(b0 + q) * 128 + col] = hp;
}

// ---------------------------------------------------------------------------
// Head: LN(gru) -> relu -> fc1 -> LN(fc1) -> relu -> fco. One block per row.
// ---------------------------------------------------------------------------
__global__ __launch_bounds__(256) void head(
    const float* __restrict__ hlast,
    const float* __restrict__ g1, const float* __restrict__ b1,
    const float* __restrict__ fc1Wt, const float* __restrict__ fc1b,
    const float* __restrict__ g2, const float* __restrict__ b2,
    const float* __restrict__ fcoWt, const float* __restrict__ fcob,
    float* __restrict__ out) {
  const int b = blockIdx.x, tid = threadIdx.x;
  __shared__ float yv[128];
  __shared__ float zv[160];
  __shared__ float red[8];
  float v = (tid < 128) ? hlast[b * 128 + tid] : 0.f;
  float p1 = v, p2 = v * v;
#pragma unroll
  for (int m = 1; m < 64; m <<= 1) { p1 += __shfl_xor(p1, m); p2 += __shfl_xor(p2, m); }
  if ((tid & 63) == 0) { red[(tid >> 6) * 2] = p1; red[(tid >> 6) * 2 + 1] = p2; }
  __syncthreads();
  float s1 = red[0] + red[2] + red[4] + red[6];
  float s2 = red[1] + red[3] + red[5] + red[7];
  float mean = s1 * (1.f / 128.f);
  float var = s2 * (1.f / 128.f) - mean * mean;
  float rs = rsqrtf(var + 1e-5f);
  if (tid < 128) yv[tid] = fmaxf((v - mean) * rs * g1[tid] + b1[tid], 0.f);
  __syncthreads();
  float z = 0.f;
  if (tid < 160) {
    z = fc1b[tid];
    for (int g = 0; g < 128; g++) z += yv[g] * fc1Wt[g * 160 + tid];
  }
  float q1 = (tid < 160) ? z : 0.f;
  float q2 = (tid < 160) ? z * z : 0.f;
#pragma unroll
  for (int m = 1; m < 64; m <<= 1) { q1 += __shfl_xor(q1, m); q2 += __shfl_xor(q2, m); }
  __syncthreads();
  if ((tid & 63) == 0) { red[(tid >> 6) * 2] = q1; red[(tid >> 6) * 2 + 1] = q2; }
  __syncthreads();
  s1 = red[0] + red[2] + red[4] + red[6];
  s2 = red[1] + red[3] + red[5] + red[7];
  mean = s1 * (1.f / 160.f);
  var = s2 * (1.f / 160.f) - mean * mean;
  rs = rsqrtf(var + 1e-5f);
  if (tid < 160) zv[tid] = fmaxf((z - mean) * rs * g2[tid] + b2[tid], 0.f);
  __syncthreads();
  if (tid < 64) {
    float o = fcob[tid];
    for (int f = 0; f < 160; f++) o += zv[f] * fcoWt[f * 64 + tid];
    out[b * 64 + tid] = o;
  }
}

// ---------------------------------------------------------------------------
// workspace layout (bytes) — gx first; scans' 1-step-over prefetch lands in
// the adjacent lout region harmlessly.
// ---------------------------------------------------------------------------
static constexpr size_t OFF_GX    = 0;                          // 268,435,456
static constexpr size_t OFF_LOUT  = 268435456;                  // 67,108,864
static constexpr size_t OFF_WIHL  = OFF_LOUT + 67108864;        // 131,072
static constexpr size_t OFF_WHHL  = OFF_WIHL + 131072;          // 131,072
static constexpr size_t OFF_WIHG  = OFF_WHHL + 131072;          // 98,304
static constexpr size_t OFF_WHHG  = OFF_WIHG + 98304;           // 98,304
static constexpr size_t OFF_BIASL = OFF_WHHG + 98304;           // 2,048
static constexpr size_t OFF_FC1T  = OFF_BIASL + 2048;           // 81,920
static constexpr size_t OFF_FCOT  = OFF_FC1T + 81920;           // 40,960
static constexpr size_t OFF_HLAST = OFF_FCOT + 40960;           // 262,144

extern "C" void kernel_launch(void* const* d_in, const int* in_sizes, int n_in,
                              void* d_out, int out_size, void* d_ws, size_t ws_size,
                              hipStream_t stream) {
  (void)in_sizes; (void)n_in; (void)out_size; (void)ws_size;
  const float* x    = (const float*)d_in[0];
  const float* lWih = (const float*)d_in[1];
  const float* lWhh = (const float*)d_in[2];
  const float* lbih = (const float*)d_in[3];
  const float* lbhh = (const float*)d_in[4];
  const float* gWih = (const float*)d_in[5];
  const float* gWhh = (const float*)d_in[6];
  const float* gbih = (const float*)d_in[7];
  const float* gbhh = (const float*)d_in[8];
  const float* lnLg = (const float*)d_in[9];
  const float* lnLb = (const float*)d_in[10];
  const float* lnGg = (const float*)d_in[11];
  const float* lnGb = (const float*)d_in[12];
  const float* fc1W = (const float*)d_in[13];
  const float* fc1b = (const float*)d_in[14];
  const float* lnFg = (const float*)d_in[15];
  const float* lnFb = (const float*)d_in[16];
  const float* fcoW = (const float*)d_in[17];
  const float* fcob = (const float*)d_in[18];

  char* ws = (char*)d_ws;
  u16* gx     = (u16*)(ws + OFF_GX);
  u16* lout   = (u16*)(ws + OFF_LOUT);
  u16* wihlb  = (u16*)(ws + OFF_WIHL);
  u16* whhlb  = (u16*)(ws + OFF_WHHL);
  u16* wihgb  = (u16*)(ws + OFF_WIHG);
  u16* whhgb  = (u16*)(ws + OFF_WHHG);
  float* biasl = (float*)(ws + OFF_BIASL);
  float* fc1Wt = (float*)(ws + OFF_FC1T);
  float* fcoWt = (float*)(ws + OFF_FCOT);
  float* hlast = (float*)(ws + OFF_HLAST);
  float* out   = (float*)d_out;

  prep_misc<<<1024, 256, 0, stream>>>(lWih, lWhh, gWih, gWhh, lbih, lbhh, fc1W, fcoW,
                                      wihlb, whhlb, wihgb, whhgb, biasl, fc1Wt, fcoWt);
  gemm_x32<<<dim3(2048, 4), 256, 0, stream>>>(x, wihlb, biasl, gx, 512);
  lstm_scan<<<128, 512, 0, stream>>>(gx, whhlb, lout);
  ln_pass<<<65536, 256, 0, stream>>>(lout, lnLg, lnLb);
  gemm_nt<<<dim3(2048, 3), 256, 0, stream>>>(lout, wihgb, gbih, gx, 384);
  gru_scan<<<128, 512, 0, stream>>>(gx, whhgb, gbhh, hlast);
  head<<<512, 256, 0, stream>>>(hlast, lnGg, lnGb, fc1Wt, fc1b, lnFg, lnFb, fcoWt, fcob, out);
}

// Round 7
// 891.455 us; speedup vs baseline: 1.7288x; 1.7288x over previous
//
#include <hip/hip_runtime.h>

// ---------------------------------------------------------------------------
// LSTMGRUHybrid: B=512, T=512, D=128, H=128 (4H=512), G=128 (3G=384), F=160, C=64
// Round 7: HSTR back to 136 (272B rows = 16B-aligned ds_read_b128; round 6
// proved stride 140 breaks alignment and costs ~75%). Input projections fused
// into the scans with ZERO M-padding via time-tiling: per 4-step group, the
// next group's x-proj is one fully-packed 16-row MFMA set (A row = 4*batch+j),
// amortized 4 MFMA/step. Both standalone GEMMs and the gx buffer are deleted.
// Pipeline: prep_x, prep_misc, lstm_scan, ln_pass, gru_scan, head.
// ---------------------------------------------------------------------------

typedef __attribute__((ext_vector_type(8))) short bf16x8;
typedef __attribute__((ext_vector_type(4))) float f32x4;
typedef __attribute__((ext_vector_type(4))) int i32x4;
typedef unsigned short u16;
typedef unsigned int u32;

#define BT 262144          // B*T
#define TT 512
#define HSTR 136           // hbuf row stride in u16: 272B = 17*16 -> aligned b128

__device__ __forceinline__ u16 f2bf(float f) {
  u32 u = __builtin_bit_cast(u32, f);
  u += 0x7fffu + ((u >> 16) & 1u);
  return (u16)(u >> 16);
}
__device__ __forceinline__ float bf2f(u16 h) {
  return __builtin_bit_cast(float, (u32)h << 16);
}
__device__ __forceinline__ u32 packbf2(float a, float b) {
  return (u32)f2bf(a) | ((u32)f2bf(b) << 16);
}
__device__ __forceinline__ bf16x8 ldg8(const u16* p) {
  return __builtin_bit_cast(bf16x8, *(const i32x4*)p);
}
// fast sigmoid/tanh: v_rcp instead of IEEE div sequence
__device__ __forceinline__ float frcp(float x) { return __builtin_amdgcn_rcpf(x); }
__device__ __forceinline__ float sigm(float x) { return frcp(1.f + __expf(-x)); }
__device__ __forceinline__ float tanh_f(float x) {
  return 1.f - 2.f * frcp(__expf(2.f * x) + 1.f);
}
// barrier draining LDS only (vmcnt stays outstanding: x-frag prefetch + lout
// stores stay off the critical path). 0xC07F = vmcnt(63) expcnt(7) lgkm(0)
__device__ __forceinline__ void scan_barrier() {
  __asm__ volatile("" ::: "memory");
  __builtin_amdgcn_s_waitcnt(0xC07F);
  __builtin_amdgcn_s_barrier();
  __asm__ volatile("" ::: "memory");
}

// ---------------------------------------------------------------------------
// prep kernels
// ---------------------------------------------------------------------------
__global__ void prep_x(const float* __restrict__ x, u16* __restrict__ xb) {
  size_t i = ((size_t)blockIdx.x * 256 + threadIdx.x) * 4;
  float4 v = *(const float4*)(x + i);
  *(uint2*)(xb + i) = make_uint2(packbf2(v.x, v.y), packbf2(v.z, v.w));
}

__global__ void prep_misc(
    const float* __restrict__ wihl, const float* __restrict__ whhl,
    const float* __restrict__ wihg, const float* __restrict__ whhg,
    const float* __restrict__ bihl, const float* __restrict__ bhhl,
    const float* __restrict__ fc1W, const float* __restrict__ fcoW,
    u16* __restrict__ wihlb, u16* __restrict__ whhlb,
    u16* __restrict__ wihgb, u16* __restrict__ whhgb,
    float* __restrict__ biasl, float* __restrict__ fc1Wt, float* __restrict__ fcoWt) {
  int i = blockIdx.x * 256 + threadIdx.x;
  if (i < 65536) {
    wihlb[i] = f2bf(wihl[i]);
  } else if (i < 131072) {
    int k = i - 65536; whhlb[k] = f2bf(whhl[k]);
  } else if (i < 180224) {
    int k = i - 131072; wihgb[k] = f2bf(wihg[k]);
  } else if (i < 229376) {
    int k = i - 180224; whhgb[k] = f2bf(whhg[k]);
  } else if (i < 229888) {
    int k = i - 229376; biasl[k] = bihl[k] + bhhl[k];
  } else if (i < 250368) {
    int k = i - 229888;                       // fc1Wt[g*160+f] = fc1W[f*128+g]
    fc1Wt[k] = fc1W[(k % 160) * 128 + (k / 160)];
  } else if (i < 260608) {
    int k = i - 250368;                       // fcoWt[f*64+c] = fcoW[c*160+f]
    fcoWt[k] = fcoW[(k % 64) * 160 + (k / 64)];
  }
}

// ---------------------------------------------------------------------------
// LSTM scan + time-tiled x-projection. 128 blocks x 512 thr; 4 batch rows at
// MFMA rows {0,4,8,12} for the recurrence (1 gate element/lane, C reg 0).
// Per 4-step group: next group's x-proj = 16 fully-packed MFMAs (A row =
// 4*batch+j), issued 4/step (one k0 slice, 4 gates). Frags for group g+2
// loaded at end of group g (>= 1 step of latency slack).
// ---------------------------------------------------------------------------
__global__ __launch_bounds__(512, 2) void lstm_scan(
    const u16* __restrict__ xb,      // [B][T][128] bf16
    const u16* __restrict__ whh,     // [512][128] bf16
    const u16* __restrict__ wih,     // [512][128] bf16
    const float* __restrict__ biasl, // [512] = bih+bhh
    u16* __restrict__ lout) {        // [B][T][128] bf16 raw h (LN later)
  const int tid = threadIdx.x;
  const int w = tid >> 6, l = tid & 63;
  const int hc = l & 15, q = l >> 4;
  const int col = w * 16 + hc;
  const int b0 = blockIdx.x * 4;
  const int mrow = q * 4;
  __shared__ __align__(16) u16 hb0[16 * HSTR];
  __shared__ __align__(16) u16 hb1[16 * HSTR];

  bf16x8 wfh[4][4], wfx[4][4];
#pragma unroll
  for (int g = 0; g < 4; g++)
#pragma unroll
    for (int k0 = 0; k0 < 4; k0++) {
      wfh[g][k0] = ldg8(&whh[(g * 128 + col) * 128 + k0 * 32 + q * 8]);
      wfx[g][k0] = ldg8(&wih[(g * 128 + col) * 128 + k0 * 32 + q * 8]);
    }
  float bsl[4];
#pragma unroll
  for (int g = 0; g < 4; g++) bsl[g] = biasl[g * 128 + col];

  float c = 0.f;
  u32 loff = (u32)(b0 + q) * (TT * 128) + col;
  const int hbase = hc * HSTR + q * 8;
  // x A-frag source: row = 4*batch + time_in_group  ->  batch=hc>>2, j=hc&3
  const u32 xbase = (u32)(b0 + (hc >> 2)) * (TT * 128) + (u32)(hc & 3) * 128 + q * 8;
  for (int i = tid; i < 16 * HSTR; i += 512) { hb0[i] = 0; hb1[i] = 0; }

  f32x4 axA[4], axB[4];   // x-proj accumulators: [gate], reg r = time j
  bf16x8 xf[4];           // frags (k0 slices) for the NEXT group's times
  {
    bf16x8 f0[4];
#pragma unroll
    for (int k0 = 0; k0 < 4; k0++) f0[k0] = ldg8(&xb[xbase + k0 * 32]);
#pragma unroll
    for (int g = 0; g < 4; g++) axA[g] = (f32x4){0.f, 0.f, 0.f, 0.f};
#pragma unroll
    for (int k0 = 0; k0 < 4; k0++)
#pragma unroll
      for (int g = 0; g < 4; g++)
        axA[g] = __builtin_amdgcn_mfma_f32_16x16x32_bf16(f0[k0], wfx[g][k0], axA[g], 0, 0, 0);
  }
#pragma unroll
  for (int k0 = 0; k0 < 4; k0++) xf[k0] = ldg8(&xb[xbase + 512 + k0 * 32]); // times 4..7
  u32 xload = xbase + 1024;  // next frag load: times 8..11
  scan_barrier();

  auto step = [&](int s, f32x4 (&axc)[4], f32x4 (&axn)[4],
                  const u16* hrd, u16* hwr) {
    // h(t-1) @ Whh^T
    bf16x8 af[4];
#pragma unroll
    for (int k0 = 0; k0 < 4; k0++) af[k0] = ldg8(&hrd[hbase + k0 * 32]);
    f32x4 ah[4];
#pragma unroll
    for (int g = 0; g < 4; g++) ah[g] = (f32x4){0.f, 0.f, 0.f, 0.f};
#pragma unroll
    for (int k0 = 0; k0 < 4; k0++)
#pragma unroll
      for (int g = 0; g < 4; g++)
        ah[g] = __builtin_amdgcn_mfma_f32_16x16x32_bf16(af[k0], wfh[g][k0], ah[g], 0, 0, 0);
    // gates: reg 0 = own (batch b0+q, col); x-proj element for time s of group
    float pi = ah[0][0] + axc[0][s] + bsl[0];
    float pf = ah[1][0] + axc[1][s] + bsl[1];
    float pg = ah[2][0] + axc[2][s] + bsl[2];
    float po = ah[3][0] + axc[3][s] + bsl[3];
    c = sigm(pf) * c + sigm(pi) * tanh_f(pg);
    float h = sigm(po) * tanh_f(c);
    u16 hv = f2bf(h);
    hwr[mrow * HSTR + col] = hv;
    lout[loff] = hv;
    loff += 128;
    // one k0 slice of next group's x-proj (independent of recurrence)
#pragma unroll
    for (int g = 0; g < 4; g++)
      axn[g] = __builtin_amdgcn_mfma_f32_16x16x32_bf16(xf[s], wfx[g][s], axn[g], 0, 0, 0);
    scan_barrier();
  };

  auto group = [&](f32x4 (&axc)[4], f32x4 (&axn)[4]) {
#pragma unroll
    for (int g = 0; g < 4; g++) axn[g] = (f32x4){0.f, 0.f, 0.f, 0.f};
    step(0, axc, axn, hb0, hb1);
    step(1, axc, axn, hb1, hb0);
    step(2, axc, axn, hb0, hb1);
    step(3, axc, axn, hb1, hb0);
    // frags for group+2 (xf[s] for s=3 consumed above; >=1 step of slack)
#pragma unroll
    for (int k0 = 0; k0 < 4; k0++) xf[k0] = ldg8(&xb[xload + k0 * 32]);
    xload += 512;
  };

#pragma unroll 1
  for (int tg = 0; tg < TT; tg += 8) {
    group(axA, axB);
    group(axB, axA);
  }
}

// ---------------------------------------------------------------------------
// In-place row LayerNorm over [BT][128] bf16. One wave per row.
// ---------------------------------------------------------------------------
__global__ __launch_bounds__(256) void ln_pass(
    u16* __restrict__ buf, const float* __restrict__ g, const float* __restrict__ b) {
  const size_t row = (size_t)blockIdx.x * 4 + (threadIdx.x >> 6);
  const int l = threadIdx.x & 63;
  u16* p = buf + row * 128 + l * 2;
  u32 v = *(const u32*)p;
  float a0 = bf2f((u16)v), a1 = bf2f((u16)(v >> 16));
  float s1 = a0 + a1, s2 = a0 * a0 + a1 * a1;
#pragma unroll
  for (int m = 1; m < 64; m <<= 1) { s1 += __shfl_xor(s1, m); s2 += __shfl_xor(s2, m); }
  float mean = s1 * 0.0078125f;
  float var = s2 * 0.0078125f - mean * mean;
  float rs = rsqrtf(var + 1e-5f);
  float2 gg = *(const float2*)(g + l * 2);
  float2 bb = *(const float2*)(b + l * 2);
  float y0 = (a0 - mean) * rs * gg.x + bb.x;
  float y1 = (a1 - mean) * rs * gg.y + bb.y;
  *(u32*)p = packbf2(y0, y1);
}

// ---------------------------------------------------------------------------
// GRU scan + time-tiled x-projection (x = LN'd lout). Same skeleton, 3 gates.
// ---------------------------------------------------------------------------
__global__ __launch_bounds__(512, 2) void gru_scan(
    const u16* __restrict__ xb,    // [B][T][128] bf16 (LN'd lstm out)
    const u16* __restrict__ whh,   // [384][128] bf16
    const u16* __restrict__ wih,   // [384][128] bf16
    const float* __restrict__ bih, const float* __restrict__ bhh,
    float* __restrict__ hlast) {   // [512][128] fp32
  const int tid = threadIdx.x;
  const int w = tid >> 6, l = tid & 63;
  const int hc = l & 15, q = l >> 4;
  const int col = w * 16 + hc;
  const int b0 = blockIdx.x * 4;
  const int mrow = q * 4;
  __shared__ __align__(16) u16 hb0[16 * HSTR];
  __shared__ __align__(16) u16 hb1[16 * HSTR];

  bf16x8 wfh[3][4], wfx[3][4];
#pragma unroll
  for (int g = 0; g < 3; g++)
#pragma unroll
    for (int k0 = 0; k0 < 4; k0++) {
      wfh[g][k0] = ldg8(&whh[(g * 128 + col) * 128 + k0 * 32 + q * 8]);
      wfx[g][k0] = ldg8(&wih[(g * 128 + col) * 128 + k0 * 32 + q * 8]);
    }
  const float brz = bih[col] + bhh[col];
  const float bzz = bih[128 + col] + bhh[128 + col];
  const float bnx = bih[256 + col], bnh = bhh[256 + col];

  float hp = 0.f;
  const int hbase = hc * HSTR + q * 8;
  const u32 xbase = (u32)(b0 + (hc >> 2)) * (TT * 128) + (u32)(hc & 3) * 128 + q * 8;
  for (int i = tid; i < 16 * HSTR; i += 512) { hb0[i] = 0; hb1[i] = 0; }

  f32x4 axA[3], axB[3];
  bf16x8 xf[4];
  {
    bf16x8 f0[4];
#pragma unroll
    for (int k0 = 0; k0 < 4; k0++) f0[k0] = ldg8(&xb[xbase + k0 * 32]);
#pragma unroll
    for (int g = 0; g < 3; g++) axA[g] = (f32x4){0.f, 0.f, 0.f, 0.f};
#pragma unroll
    for (int k0 = 0; k0 < 4; k0++)
#pragma unroll
      for (int g = 0; g < 3; g++)
        axA[g] = __builtin_amdgcn_mfma_f32_16x16x32_bf16(f0[k0], wfx[g][k0], axA[g], 0, 0, 0);
  }
#pragma unroll
  for (int k0 = 0; k0 < 4; k0++) xf[k0] = ldg8(&xb[xbase + 512 + k0 * 32]);
  u32 xload = xbase + 1024;
  scan_barrier();

  auto step = [&](int s, f32x4 (&axc)[3], f32x4 (&axn)[3],
                  const u16* hrd, u16* hwr) {
    bf16x8 af[4];
#pragma unroll
    for (int k0 = 0; k0 < 4; k0++) af[k0] = ldg8(&hrd[hbase + k0 * 32]);
    f32x4 ah[3];
#pragma unroll
    for (int g = 0; g < 3; g++) ah[g] = (f32x4){0.f, 0.f, 0.f, 0.f};
#pragma unroll
    for (int k0 = 0; k0 < 4; k0++)
#pragma unroll
      for (int g = 0; g < 3; g++)
        ah[g] = __builtin_amdgcn_mfma_f32_16x16x32_bf16(af[k0], wfh[g][k0], ah[g], 0, 0, 0);
    float rr = sigm(axc[0][s] + ah[0][0] + brz);
    float zz = sigm(axc[1][s] + ah[1][0] + bzz);
    float nn = tanh_f(axc[2][s] + bnx + rr * (ah[2][0] + bnh));
    hp = nn + zz * (hp - nn);
    hwr[mrow * HSTR + col] = f2bf(hp);
#pragma unroll
    for (int g = 0; g < 3; g++)
      axn[g] = __builtin_amdgcn_mfma_f32_16x16x32_bf16(xf[s], wfx[g][s], axn[g], 0, 0, 0);
    scan_barrier();
  };

  auto group = [&](f32x4 (&axc)[3], f32x4 (&axn)[3]) {
#pragma unroll
    for (int g = 0; g < 3; g++) axn[g] = (f32x4){0.f, 0.f, 0.f, 0.f};
    step(0, axc, axn, hb0, hb1);
    step(1, axc, axn, hb1, hb0);
    step(2, axc, axn, hb0, hb1);
    step(3, axc, axn, hb1, hb0);
#pragma unroll
    for (int k0 = 0; k0 < 4; k0++) xf[k0] = ldg8(&xb[xload + k0 * 32]);
    xload += 512;
  };

#pragma unroll 1
  for (int tg = 0; tg < TT; tg += 8) {
    group(axA, axB);
    group(axB, axA);
  }
  hlast[(size_t)(b0 + q) * 128 + col] = hp;
}

// ---------------------------------------------------------------------------
// Head: LN(gru) -> relu -> fc1 -> LN(fc1) -> relu -> fco. One block per row.
// ---------------------------------------------------------------------------
__global__ __launch_bounds__(256) void head(
    const float* __restrict__ hlast,
    const float* __restrict__ g1, const float* __restrict__ b1,
    const float* __restrict__ fc1Wt, const float* __restrict__ fc1b,
    const float* __restrict__ g2, const float* __restrict__ b2,
    const float* __restrict__ fcoWt, const float* __restrict__ fcob,
    float* __restrict__ out) {
  const int b = blockIdx.x, tid = threadIdx.x;
  __shared__ float yv[128];
  __shared__ float zv[160];
  __shared__ float red[8];
  float v = (tid < 128) ? hlast[b * 128 + tid] : 0.f;
  float p1 = v, p2 = v * v;
#pragma unroll
  for (int m = 1; m < 64; m <<= 1) { p1 += __shfl_xor(p1, m); p2 += __shfl_xor(p2, m); }
  if ((tid & 63) == 0) { red[(tid >> 6) * 2] = p1; red[(tid >> 6) * 2 + 1] = p2; }
  __syncthreads();
  float s1 = red[0] + red[2] + red[4] + red[6];
  float s2 = red[1] + red[3] + red[5] + red[7];
  float mean = s1 * (1.f / 128.f);
  float var = s2 * (1.f / 128.f) - mean * mean;
  float rs = rsqrtf(var + 1e-5f);
  if (tid < 128) yv[tid] = fmaxf((v - mean) * rs * g1[tid] + b1[tid], 0.f);
  __syncthreads();
  float z = 0.f;
  if (tid < 160) {
    z = fc1b[tid];
    for (int g = 0; g < 128; g++) z += yv[g] * fc1Wt[g * 160 + tid];
  }
  float q1 = (tid < 160) ? z : 0.f;
  float q2 = (tid < 160) ? z * z : 0.f;
#pragma unroll
  for (int m = 1; m < 64; m <<= 1) { q1 += __shfl_xor(q1, m); q2 += __shfl_xor(q2, m); }
  __syncthreads();
  if ((tid & 63) == 0) { red[(tid >> 6) * 2] = q1; red[(tid >> 6) * 2 + 1] = q2; }
  __syncthreads();
  s1 = red[0] + red[2] + red[4] + red[6];
  s2 = red[1] + red[3] + red[5] + red[7];
  mean = s1 * (1.f / 160.f);
  var = s2 * (1.f / 160.f) - mean * mean;
  rs = rsqrtf(var + 1e-5f);
  if (tid < 160) zv[tid] = fmaxf((z - mean) * rs * g2[tid] + b2[tid], 0.f);
  __syncthreads();
  if (tid < 64) {
    float o = fcob[tid];
    for (int f = 0; f < 160; f++) o += zv[f] * fcoWt[f * 64 + tid];
    out[b * 64 + tid] = o;
  }
}

// ---------------------------------------------------------------------------
// workspace layout (bytes): xbf then lout first — the scans' 1-group-ahead
// frag prefetch overruns by <2KB into the adjacent region harmlessly.
// ---------------------------------------------------------------------------
static constexpr size_t OFF_XBF   = 0;                          // 67,108,864
static constexpr size_t OFF_LOUT  = 67108864;                   // 67,108,864
static constexpr size_t OFF_WIHL  = OFF_LOUT + 67108864;        // 131,072
static constexpr size_t OFF_WHHL  = OFF_WIHL + 131072;          // 131,072
static constexpr size_t OFF_WIHG  = OFF_WHHL + 131072;          // 98,304
static constexpr size_t OFF_WHHG  = OFF_WIHG + 98304;           // 98,304
static constexpr size_t OFF_BIASL = OFF_WHHG + 98304;           // 2,048
static constexpr size_t OFF_FC1T  = OFF_BIASL + 2048;           // 81,920
static constexpr size_t OFF_FCOT  = OFF_FC1T + 81920;           // 40,960
static constexpr size_t OFF_HLAST = OFF_FCOT + 40960;           // 262,144

extern "C" void kernel_launch(void* const* d_in, const int* in_sizes, int n_in,
                              void* d_out, int out_size, void* d_ws, size_t ws_size,
                              hipStream_t stream) {
  (void)in_sizes; (void)n_in; (void)out_size; (void)ws_size;
  const float* x    = (const float*)d_in[0];
  const float* lWih = (const float*)d_in[1];
  const float* lWhh = (const float*)d_in[2];
  const float* lbih = (const float*)d_in[3];
  const float* lbhh = (const float*)d_in[4];
  const float* gWih = (const float*)d_in[5];
  const float* gWhh = (const float*)d_in[6];
  const float* gbih = (const float*)d_in[7];
  const float* gbhh = (const float*)d_in[8];
  const float* lnLg = (const float*)d_in[9];
  const float* lnLb = (const float*)d_in[10];
  const float* lnGg = (const float*)d_in[11];
  const float* lnGb = (const float*)d_in[12];
  const float* fc1W = (const float*)d_in[13];
  const float* fc1b = (const float*)d_in[14];
  const float* lnFg = (const float*)d_in[15];
  const float* lnFb = (const float*)d_in[16];
  const float* fcoW = (const float*)d_in[17];
  const float* fcob = (const float*)d_in[18];

  char* ws = (char*)d_ws;
  u16* xbf    = (u16*)(ws + OFF_XBF);
  u16* lout   = (u16*)(ws + OFF_LOUT);
  u16* wihlb  = (u16*)(ws + OFF_WIHL);
  u16* whhlb  = (u16*)(ws + OFF_WHHL);
  u16* wihgb  = (u16*)(ws + OFF_WIHG);
  u16* whhgb  = (u16*)(ws + OFF_WHHG);
  float* biasl = (float*)(ws + OFF_BIASL);
  float* fc1Wt = (float*)(ws + OFF_FC1T);
  float* fcoWt = (float*)(ws + OFF_FCOT);
  float* hlast = (float*)(ws + OFF_HLAST);
  float* out   = (float*)d_out;

  prep_x<<<32768, 256, 0, stream>>>(x, xbf);
  prep_misc<<<1024, 256, 0, stream>>>(lWih, lWhh, gWih, gWhh, lbih, lbhh, fc1W, fcoW,
                                      wihlb, whhlb, wihgb, whhgb, biasl, fc1Wt, fcoWt);
  lstm_scan<<<128, 512, 0, stream>>>(xbf, whhlb, wihlb, biasl, lout);
  ln_pass<<<65536, 256, 0, stream>>>(lout, lnLg, lnLb);
  gru_scan<<<128, 512, 0, stream>>>(lout, whhgb, wihgb, gbih, gbhh, hlast);
  head<<<512, 256, 0, stream>>>(hlast, lnGg, lnGb, fc1Wt, fc1b, lnFg, lnFb, fcoWt, fcob, out);
}